// Round 1
// baseline (593.977 us; speedup 1.0000x reference)
//
#include <hip/hip_runtime.h>
#include <math.h>

#define TOPK   4
#define NBINS  33          // MAX_NUM_BINS + 1
#define SIDES  4
#define CPA    132         // corners per anchor = 4*33
#define STATD  20
#define HID    64
#define NCLS   80
#define APB    64          // anchors per block
#define BS     256

__global__ __launch_bounds__(BS) void lqe_kernel(
    const float* __restrict__ scores,
    const float* __restrict__ corners,
    const float* __restrict__ W1,    // (20,64) row-major
    const float* __restrict__ b1,    // (64)
    const float* __restrict__ W2,    // (64,1)
    const float* __restrict__ b2,    // (1)
    float* __restrict__ out)
{
    __shared__ float s_corners[APB * CPA];    // 33792 B
    __shared__ float s_stat[APB * STATD];     //  5120 B
    __shared__ float s_q[APB];
    __shared__ float s_W1[STATD * HID];       //  5120 B
    __shared__ float s_b1[HID];
    __shared__ float s_W2[HID];
    __shared__ float s_b2;

    const int tid = threadIdx.x;
    const long long aBase = (long long)blockIdx.x * APB;

    // ---- stage MLP weights ----
    for (int i = tid; i < STATD * HID; i += BS) s_W1[i] = W1[i];
    if (tid < HID) { s_b1[tid] = b1[tid]; s_W2[tid] = W2[tid]; }
    if (tid == 0)  { s_b2 = b2[0]; }

    // ---- stage corners (coalesced float4): 64*132/4 = 2112 vec4 ----
    {
        const float4* src = (const float4*)(corners + aBase * CPA);
        float4* dst = (float4*)s_corners;
        #pragma unroll
        for (int i = tid; i < (APB * CPA) / 4; i += BS) dst[i] = src[i];
    }
    __syncthreads();

    // ---- phase 1a: softmax + top-4 per (anchor, side) ----
    {
        const int a    = tid >> 2;
        const int side = tid & 3;
        const float* pc = s_corners + a * CPA + side * NBINS;  // addr = 33*tid

        float p[NBINS];
        #pragma unroll
        for (int k = 0; k < NBINS; ++k) p[k] = pc[k];

        float m = p[0];
        #pragma unroll
        for (int k = 1; k < NBINS; ++k) m = fmaxf(m, p[k]);

        float s = 0.0f;
        #pragma unroll
        for (int k = 0; k < NBINS; ++k) { p[k] = __expf(p[k] - m); s += p[k]; }

        // selection of top-4 (descending) on un-normalized exps
        float top[TOPK];
        #pragma unroll
        for (int j = 0; j < TOPK; ++j) {
            float best = -1.0f; int bi = 0;
            #pragma unroll
            for (int k = 0; k < NBINS; ++k) {
                if (p[k] > best) { best = p[k]; bi = k; }
            }
            top[j] = best;
            #pragma unroll
            for (int k = 0; k < NBINS; ++k) p[k] = (k == bi) ? -1.0f : p[k];
        }

        const float inv = 1.0f / s;
        const float t0 = top[0] * inv, t1 = top[1] * inv;
        const float t2 = top[2] * inv, t3 = top[3] * inv;
        const float mean = (t0 + t1 + t2 + t3) * 0.25f;

        float* st = s_stat + a * STATD + side * (TOPK + 1);    // addr = 5*tid
        st[0] = t0; st[1] = t1; st[2] = t2; st[3] = t3; st[4] = mean;
    }
    __syncthreads();

    // ---- phase 1b: MLP 20->64->1, one wave per anchor, lane = hidden unit ----
    {
        const int wave = tid >> 6;
        const int lane = tid & 63;
        #pragma unroll
        for (int i = 0; i < APB / 4; ++i) {        // 16 anchors per wave
            const int a = wave * (APB / 4) + i;
            float acc = s_b1[lane];
            #pragma unroll
            for (int d = 0; d < STATD; ++d)
                acc = fmaf(s_stat[a * STATD + d], s_W1[d * HID + lane], acc);
            float hv = fmaxf(acc, 0.0f) * s_W2[lane];
            #pragma unroll
            for (int mk = 32; mk >= 1; mk >>= 1)
                hv += __shfl_xor(hv, mk, 64);
            if (lane == 0) s_q[a] = hv + s_b2;
        }
    }
    __syncthreads();

    // ---- phase 2: out = scores + quality (coalesced float4) ----
    {
        const float4* sc = (const float4*)(scores + aBase * NCLS);
        float4* op = (float4*)(out + aBase * NCLS);
        #pragma unroll
        for (int j = tid; j < (APB * NCLS) / 4; j += BS) {   // 1280 vec4, 5 iters
            const float q = s_q[j / (NCLS / 4)];
            float4 v = sc[j];
            v.x += q; v.y += q; v.z += q; v.w += q;
            op[j] = v;
        }
    }
}

extern "C" void kernel_launch(void* const* d_in, const int* in_sizes, int n_in,
                              void* d_out, int out_size, void* d_ws, size_t ws_size,
                              hipStream_t stream) {
    const float* scores  = (const float*)d_in[0];
    const float* corners = (const float*)d_in[1];
    const float* W1      = (const float*)d_in[2];
    const float* b1      = (const float*)d_in[3];
    const float* W2      = (const float*)d_in[4];
    const float* b2      = (const float*)d_in[5];
    float* out = (float*)d_out;

    const int nAnchors = in_sizes[0] / NCLS;          // 524288
    const int blocks = nAnchors / APB;                // 8192 (exact)
    lqe_kernel<<<blocks, BS, 0, stream>>>(scores, corners, W1, b1, W2, b2, out);
}

// Round 2
// 544.939 us; speedup vs baseline: 1.0900x; 1.0900x over previous
//
#include <hip/hip_runtime.h>
#include <math.h>

#define TOPK   4
#define NBINS  33          // MAX_NUM_BINS + 1
#define CPA    132         // corners per anchor = 4*33
#define STATD  20
#define HID    64
#define NCLS   80
#define APB    64          // anchors per block
#define BS     256

// ---------------- K1: per-anchor quality -> q[] ----------------
__global__ __launch_bounds__(BS, 4) void lqe_quality(
    const float* __restrict__ corners,
    const float* __restrict__ W1,    // (20,64) row-major
    const float* __restrict__ b1,    // (64)
    const float* __restrict__ W2,    // (64,1)
    const float* __restrict__ b2,    // (1)
    float* __restrict__ q)           // (nAnchors)
{
    __shared__ float s_corners[APB * CPA];    // 33792 B
    __shared__ float s_stat[APB * STATD];     //  5120 B

    const int tid  = threadIdx.x;
    const int lane = tid & 63;
    const long long aBase = (long long)blockIdx.x * APB;

    // W1 column + biases in registers (coalesced: lane l reads W1[d*64+l])
    float w1c[STATD];
    #pragma unroll
    for (int d = 0; d < STATD; ++d) w1c[d] = W1[d * HID + lane];
    const float bias = b1[lane];
    const float w2v  = W2[lane];

    // stage corners (coalesced float4): 2112 vec4, 8.25/thread
    {
        const float4* src = (const float4*)(corners + aBase * CPA);
        float4* dst = (float4*)s_corners;
        #pragma unroll
        for (int i = tid; i < (APB * CPA) / 4; i += BS) dst[i] = src[i];
    }
    __syncthreads();

    // ---- phase 1a: softmax + top-4, thread = (anchor, side) ----
    {
        const int a    = tid >> 2;
        const int side = tid & 3;
        const float* pc = s_corners + a * CPA + side * NBINS;  // 33*tid: conflict-free

        float p[NBINS];
        #pragma unroll
        for (int k = 0; k < NBINS; ++k) p[k] = pc[k];

        float m = p[0];
        #pragma unroll
        for (int k = 1; k < NBINS; ++k) m = fmaxf(m, p[k]);

        float s = 0.0f;
        #pragma unroll
        for (int k = 0; k < NBINS; ++k) { p[k] = __expf(p[k] - m); s += p[k]; }

        // top-4 via branchless insertion network (exps > 0, so -1 is safe init)
        float t0 = -1.0f, t1 = -1.0f, t2 = -1.0f, t3 = -1.0f;
        #pragma unroll
        for (int k = 0; k < NBINS; ++k) {
            const float v  = p[k];
            const float b0 = fmaxf(t0, v),  c0 = fminf(t0, v);
            const float b1_ = fmaxf(t1, c0), c1 = fminf(t1, c0);
            const float b2_ = fmaxf(t2, c1), c2 = fminf(t2, c1);
            const float b3 = fmaxf(t3, c2);
            t0 = b0; t1 = b1_; t2 = b2_; t3 = b3;
        }

        const float inv = 1.0f / s;
        t0 *= inv; t1 *= inv; t2 *= inv; t3 *= inv;
        const float mean = (t0 + t1 + t2 + t3) * 0.25f;

        float* st = s_stat + a * STATD + side * (TOPK + 1);    // 5*tid: conflict-free
        st[0] = t0; st[1] = t1; st[2] = t2; st[3] = t3; st[4] = mean;
    }
    __syncthreads();

    // ---- phase 1b: MLP 20->64->1; wave handles 16 anchors, lane = hidden unit ----
    {
        const int wave = tid >> 6;
        const float b2v = b2[0];
        #pragma unroll
        for (int i = 0; i < APB / 4; ++i) {
            const int a = wave * (APB / 4) + i;
            // stat: 5 broadcast ds_read_b128 (a*20 floats = 80 B, 16B-aligned)
            const float4* sp = (const float4*)(s_stat + a * STATD);
            const float4 s0 = sp[0], s1 = sp[1], s2 = sp[2], s3 = sp[3], s4 = sp[4];
            float acc = bias;
            acc = fmaf(s0.x, w1c[0],  acc); acc = fmaf(s0.y, w1c[1],  acc);
            acc = fmaf(s0.z, w1c[2],  acc); acc = fmaf(s0.w, w1c[3],  acc);
            acc = fmaf(s1.x, w1c[4],  acc); acc = fmaf(s1.y, w1c[5],  acc);
            acc = fmaf(s1.z, w1c[6],  acc); acc = fmaf(s1.w, w1c[7],  acc);
            acc = fmaf(s2.x, w1c[8],  acc); acc = fmaf(s2.y, w1c[9],  acc);
            acc = fmaf(s2.z, w1c[10], acc); acc = fmaf(s2.w, w1c[11], acc);
            acc = fmaf(s3.x, w1c[12], acc); acc = fmaf(s3.y, w1c[13], acc);
            acc = fmaf(s3.z, w1c[14], acc); acc = fmaf(s3.w, w1c[15], acc);
            acc = fmaf(s4.x, w1c[16], acc); acc = fmaf(s4.y, w1c[17], acc);
            acc = fmaf(s4.z, w1c[18], acc); acc = fmaf(s4.w, w1c[19], acc);
            float hv = fmaxf(acc, 0.0f) * w2v;
            #pragma unroll
            for (int mk = 32; mk >= 1; mk >>= 1)
                hv += __shfl_xor(hv, mk, 64);
            if (lane == 0) q[aBase + a] = hv + b2v;
        }
    }
}

// ---------------- K2: out = scores + q (pure streaming) ----------------
__global__ __launch_bounds__(BS) void lqe_add(
    const float* __restrict__ scores,
    const float* __restrict__ q,
    float* __restrict__ out)
{
    __shared__ float s_q[APB];
    const int tid = threadIdx.x;
    const long long aBase = (long long)blockIdx.x * APB;

    if (tid < APB) s_q[tid] = q[aBase + tid];
    __syncthreads();

    const float4* sc = (const float4*)(scores + aBase * NCLS);
    float4* op = (float4*)(out + aBase * NCLS);
    #pragma unroll
    for (int j = tid; j < (APB * NCLS) / 4; j += BS) {   // 1280 vec4, 5 iters
        const float qv = s_q[j / (NCLS / 4)];
        float4 v = sc[j];
        v.x += qv; v.y += qv; v.z += qv; v.w += qv;
        op[j] = v;
    }
}

extern "C" void kernel_launch(void* const* d_in, const int* in_sizes, int n_in,
                              void* d_out, int out_size, void* d_ws, size_t ws_size,
                              hipStream_t stream) {
    const float* scores  = (const float*)d_in[0];
    const float* corners = (const float*)d_in[1];
    const float* W1      = (const float*)d_in[2];
    const float* b1      = (const float*)d_in[3];
    const float* W2      = (const float*)d_in[4];
    const float* b2      = (const float*)d_in[5];
    float* out = (float*)d_out;
    float* q   = (float*)d_ws;                        // nAnchors floats (2 MB)

    const int nAnchors = in_sizes[0] / NCLS;          // 524288
    const int blocks   = nAnchors / APB;              // 8192 (exact)

    lqe_quality<<<blocks, BS, 0, stream>>>(corners, W1, b1, W2, b2, q);
    lqe_add<<<blocks, BS, 0, stream>>>(scores, q, out);
}